// Round 5
// baseline (361.268 us; speedup 1.0000x reference)
//
#include <hip/hip_runtime.h>

#define NPOINTS 262144
#define SUMH 224
#define SUMW 221
#define NREG 500

// ---------- DPP helpers ----------
__device__ __forceinline__ float rlane(float v, int l) {
  return __int_as_float(__builtin_amdgcn_readlane(__float_as_int(v), l));
}
template<int CTRL>
__device__ __forceinline__ float dpp0(float x) {   // 0-fill on invalid
  return __int_as_float(__builtin_amdgcn_update_dpp(0, __float_as_int(x), CTRL, 0xF, 0xF, true));
}
template<int CTRL, int RM>
__device__ __forceinline__ float dpp_rm(float x) { // row-masked, old=0
  return __int_as_float(__builtin_amdgcn_update_dpp(0, __float_as_int(x), CTRL, RM, 0xF, false));
}
template<int CTRL>
__device__ __forceinline__ float dpp_max_(float x) {
  return fmaxf(x, __int_as_float(__builtin_amdgcn_update_dpp(__float_as_int(x), __float_as_int(x), CTRL, 0xF, 0xF, false)));
}
// 64-lane reduce / scan (region kernel)
__device__ __forceinline__ float wave_sum(float x) {
  x += dpp0<0x111>(x); x += dpp0<0x112>(x); x += dpp0<0x114>(x); x += dpp0<0x118>(x);
  x += dpp_rm<0x142, 0xA>(x); x += dpp_rm<0x143, 0xC>(x);
  return rlane(x, 63);
}
__device__ __forceinline__ float wave_max(float x) {
  x = dpp_max_<0x111>(x); x = dpp_max_<0x112>(x); x = dpp_max_<0x114>(x);
  x = dpp_max_<0x118>(x); x = dpp_max_<0x142>(x); x = dpp_max_<0x143>(x);
  return rlane(x, 63);
}
__device__ __forceinline__ float wave_scan_incl(float x) {
  x += dpp0<0x111>(x); x += dpp0<0x112>(x); x += dpp0<0x114>(x); x += dpp0<0x118>(x);
  x += dpp_rm<0x142, 0xA>(x);   // row_bcast:15 -> rows 1,3
  x += dpp_rm<0x143, 0xC>(x);   // row_bcast:31 -> rows 2,3
  return x;
}
// 32-lane group sum: 16-lane DPP butterfly + xor16 via ds_swizzle
__device__ __forceinline__ float grp32_sum(float x) {
  x += dpp0<0xB1>(x);    // xor1 (quad_perm)
  x += dpp0<0x4E>(x);    // xor2
  x += dpp0<0x141>(x);   // row_half_mirror (xor7 after xor1/2 -> acts as xor4)
  x += dpp0<0x140>(x);   // row_mirror (xor15 -> acts as xor8)
  x += __int_as_float(__builtin_amdgcn_ds_swizzle(__float_as_int(x), 0x401F)); // xor16
  return x;
}
__device__ __forceinline__ float bperm(int byteidx, float v) {
  return __int_as_float(__builtin_amdgcn_ds_bpermute(byteidx, __float_as_int(v)));
}

// ---------- Kernel 1: per-ROI tables ----------
// Per rix (stride SUMH floats), level slots {0..127, 128..191, 192..223}:
//   BL[j] = bin edge j (BL[0]=0, BL[n-1]=1)
//   HW[j] = 0.5*w_j                (0 for j=n-1)
//   HS[j] = 0.5*(w_{j-1} + w_j)    (trapezoid weight; w_{-1}=w_{n-1}=0)

template<int M, int SRC, int DST, int NB>
__device__ __forceinline__ void region_level(const float* __restrict__ wrow,
    float* __restrict__ BL, float* __restrict__ HW, float* __restrict__ HS,
    int lane, float* lds)
{
  float v0 = (lane < M) ? wrow[SRC + lane] : -1e30f;
  float v1 = -1e30f;
  if constexpr (NB == 128) { if (lane + 64 < M) v1 = wrow[SRC + lane + 64]; }
  float m = wave_max(fmaxf(v0, v1));
  float e0 = __expf(v0 - m);                 // 0 for padded slots
  float e1 = (NB == 128) ? __expf(v1 - m) : 0.0f;
  float s = wave_sum(e0 + e1);
  float inv = 1.0f / s;
  if (lane < NB) lds[lane] = e0;
  if constexpr (NB == 128) lds[lane + 64] = e1;
  __syncthreads();
  if (lane < NB) {
    HW[DST + lane] = 0.5f * e0 * inv;
    float prev = (lane == 0) ? 0.0f : lds[lane - 1];
    HS[DST + lane] = 0.5f * (e0 + prev) * inv;
  }
  if constexpr (NB == 128) {
    HW[DST + lane + 64] = 0.5f * e1 * inv;
    HS[DST + lane + 64] = 0.5f * (e1 + lds[lane + 63]) * inv;
  }
  float incl0 = wave_scan_incl(e0);
  if (lane == 0) BL[DST] = 0.0f;
  if (lane < M) BL[DST + 1 + lane] = (lane == M - 1) ? 1.0f : incl0 * inv;
  if constexpr (NB == 128) {
    float incl1 = wave_scan_incl(e1) + rlane(incl0, 63);
    int k = 64 + lane;
    if (k < M) BL[DST + 1 + k] = (k == M - 1) ? 1.0f : incl1 * inv;
  }
  __syncthreads();
}

__global__ void __launch_bounds__(64) region_kernel(
    const int* __restrict__ roi, const float* __restrict__ wemb,
    float* __restrict__ wsBL, float* __restrict__ wsHW, float* __restrict__ wsHS)
{
  __shared__ float lds[128];
  int rix = blockIdx.x;
  int lane = threadIdx.x;
  int greg = roi[rix];
  const float* wrow = wemb + (size_t)greg * SUMW;
  float* BL = wsBL + (size_t)rix * SUMH;
  float* HW = wsHW + (size_t)rix * SUMH;
  float* HS = wsHS + (size_t)rix * SUMH;
  region_level<127,   0,   0, 128>(wrow, BL, HW, HS, lane, lds);
  region_level< 63, 127, 128,  64>(wrow, BL, HW, HS, lane, lds);
  region_level< 31, 190, 192,  32>(wrow, BL, HW, HS, lane, lds);
}

// ---------- Kernel 2: 2 points/wave, 32-lane groups, masked-reduction apply ----------

template<int OFF, int C>
__device__ __forceinline__ void prep(const float* __restrict__ U,
    const float* __restrict__ D, const float* __restrict__ BLt,
    const float* __restrict__ HWt, const float* __restrict__ HSt, int s,
    float (&he)[C], float (&t)[C], float (&bl)[C], float (&hw)[C],
    float& larea, float& invarea)
{
  if constexpr (C == 4) {
    int c0 = OFF + s * 4;
    float4 a = *(const float4*)(U   + c0);
    float4 b = *(const float4*)(D   + c0);
    float4 e = *(const float4*)(BLt + c0);
    float4 f = *(const float4*)(HWt + c0);
    float4 g = *(const float4*)(HSt + c0);
    he[0] = __expf(a.x + b.x); he[1] = __expf(a.y + b.y);
    he[2] = __expf(a.z + b.z); he[3] = __expf(a.w + b.w);
    t[0] = he[0] * g.x; t[1] = he[1] * g.y; t[2] = he[2] * g.z; t[3] = he[3] * g.w;
    bl[0] = e.x; bl[1] = e.y; bl[2] = e.z; bl[3] = e.w;
    hw[0] = f.x; hw[1] = f.y; hw[2] = f.z; hw[3] = f.w;
  } else if constexpr (C == 2) {
    int c0 = OFF + s * 2;
    float2 a = *(const float2*)(U   + c0);
    float2 b = *(const float2*)(D   + c0);
    float2 e = *(const float2*)(BLt + c0);
    float2 f = *(const float2*)(HWt + c0);
    float2 g = *(const float2*)(HSt + c0);
    he[0] = __expf(a.x + b.x); he[1] = __expf(a.y + b.y);
    t[0] = he[0] * g.x; t[1] = he[1] * g.y;
    bl[0] = e.x; bl[1] = e.y; hw[0] = f.x; hw[1] = f.y;
  } else {
    int c0 = OFF + s;
    he[0] = __expf(U[c0] + D[c0]);
    t[0]  = he[0] * HSt[c0];
    bl[0] = BLt[c0];
    hw[0] = HWt[c0];
  }
  float a_ = 0.0f;
#pragma unroll
  for (int i = 0; i < C; ++i) a_ += t[i];
  float area = grp32_sum(a_);
  larea = __log2f(area);
  invarea = __builtin_amdgcn_rcpf(area);
}

template<int C>
__device__ __forceinline__ void apply(float& xv, float& logdet, int s, int nb_idx,
    const float (&he)[C], const float (&t)[C], const float (&bl)[C],
    const float (&hw)[C], float larea, float invarea)
{
  float f[C];
#pragma unroll
  for (int i = 0; i < C; ++i) f[i] = (bl[i] < xv) ? 1.0f : 0.0f;
  if (s == 0)  f[0]     = 1.0f;   // edge 0 always counted (clamp-low)
  if (s == 31) f[C - 1] = 0.0f;   // last edge never counted (clamp-high)
  // neighbor firsts from next lane; cross-group garbage only feeds forced-zero slot
  float fN  = bperm(nb_idx, f[0]);
  float heN = bperm(nb_idx, he[0]);
  float hl = 0.0f, hr = 0.0f, loc = 0.0f, hwm = 0.0f, pt = 0.0f;
#pragma unroll
  for (int i = 0; i < C; ++i) {
    float fnext  = (i < C - 1) ? f[i + 1]  : fN;
    float henext = (i < C - 1) ? he[i + 1] : heN;
    float mi = f[i] * (1.0f - fnext);   // one-hot at bin bi
    hl  += he[i] * mi;
    hr  += henext * mi;
    loc += bl[i] * mi;
    hwm += hw[i] * mi;
    pt  += t[i] * f[i];                 // inclusive trapezoid sum through bi
  }
  hl  = grp32_sum(hl);
  hr  = grp32_sum(hr);
  loc = grp32_sum(loc);
  hwm = grp32_sum(hwm);
  pt  = grp32_sum(pt);
  float part = pt - hl * hwm;           // unnormalized cdf at left edge of bin
  float inw = 2.0f * hwm;
  float alpha = (xv - loc) * __builtin_amdgcn_rcpf(inw);
  float dh = hr - hl;
  xv = ((0.5f * dh * alpha + hl) * alpha * inw + part) * invarea;
  logdet += (__log2f(alpha * dh + hl) - larea) * 0.69314718055994531f;
}

__global__ void __launch_bounds__(256, 8) spline_kernel(
    const float* __restrict__ x, const int* __restrict__ roi,
    const int* __restrict__ lix, const float* __restrict__ delta,
    const float* __restrict__ hemb,
    const float* __restrict__ wsBL, const float* __restrict__ wsHW,
    const float* __restrict__ wsHS, float* __restrict__ out)
{
  int tid  = (int)(blockIdx.x * blockDim.x + threadIdx.x);
  int wid  = tid >> 6;
  int lane = (int)(threadIdx.x & 63);
  int grp  = lane >> 5;            // 2 points per wave
  int s    = lane & 31;            // 32-lane group, lanes <-> columns
  int pid  = wid * 2 + grp;
  int nb_idx = ((lane + 1) & 63) << 2;   // bpermute byte index of next lane

  float xv = x[pid];               // group-uniform
  int r    = lix[pid];
  int greg = roi[r];
  const float* U   = hemb  + (size_t)greg * SUMH;
  const float* D   = delta + (size_t)pid  * SUMH;
  const float* BLt = wsBL  + (size_t)r    * SUMH;
  const float* HWt = wsHW  + (size_t)r    * SUMH;
  const float* HSt = wsHS  + (size_t)r    * SUMH;

  float he0[4], t0[4], bl0[4], hw0[4], la0, ia0;
  float he1[2], t1[2], bl1[2], hw1[2], la1, ia1;
  float he2[1], t2[1], bl2[1], hw2[1], la2, ia2;
  prep<  0, 4>(U, D, BLt, HWt, HSt, s, he0, t0, bl0, hw0, la0, ia0);
  prep<128, 2>(U, D, BLt, HWt, HSt, s, he1, t1, bl1, hw1, la1, ia1);
  prep<192, 1>(U, D, BLt, HWt, HSt, s, he2, t2, bl2, hw2, la2, ia2);

  float logdet = 0.0f;
  apply<4>(xv, logdet, s, nb_idx, he0, t0, bl0, hw0, la0, ia0);
  apply<2>(xv, logdet, s, nb_idx, he1, t1, bl1, hw1, la1, ia1);
  apply<1>(xv, logdet, s, nb_idx, he2, t2, bl2, hw2, la2, ia2);

  if (s == 0) {
    out[pid] = xv;
    out[NPOINTS + pid] = logdet;
  }
}

// ---------- launch ----------

extern "C" void kernel_launch(void* const* d_in, const int* in_sizes, int n_in,
                              void* d_out, int out_size, void* d_ws, size_t ws_size,
                              hipStream_t stream) {
  const float* x     = (const float*)d_in[0];
  const int*   roi   = (const int*)  d_in[1];
  const int*   lix   = (const int*)  d_in[2];
  const float* delta = (const float*)d_in[3];
  const float* hemb  = (const float*)d_in[4];
  const float* wemb  = (const float*)d_in[5];

  float* wsBL = (float*)d_ws;                    // [500][224]
  float* wsHW = wsBL + (size_t)NREG * SUMH;      // [500][224]
  float* wsHS = wsHW + (size_t)NREG * SUMH;      // [500][224]

  region_kernel<<<NREG, 64, 0, stream>>>(roi, wemb, wsBL, wsHW, wsHS);
  spline_kernel<<<NPOINTS / 8, 256, 0, stream>>>(x, roi, lix, delta, hemb,
                                                 wsBL, wsHW, wsHS, (float*)d_out);
}